// Round 3
// baseline (1359.627 us; speedup 1.0000x reference)
//
#include <hip/hip_runtime.h>
#include <hip/hip_bf16.h>

#define TT   4096
#define HH   1024
#define FF   3584
#define EE   8
#define N13  7168   // 2*FF (interleaved w1/w3 at 16-col granularity)
#define TKP  8192   // TT * top_k

#define BM 128
#define BN 128
#define BK 64
#define KSPLIT 4
#define KCH (FF / KSPLIT)   // 896 = 14 iters of BK

// prep kernel region sizes (blocks of 256)
#define NB13 57344
#define NBW2 28672
#define NBX  4096
#define NBR  1024

typedef unsigned short u16;
typedef __attribute__((ext_vector_type(8))) short short8;
typedef __attribute__((ext_vector_type(4))) float floatx4;

__device__ __forceinline__ u16 f2b(float f) {
  union { float f; unsigned u; } v; v.f = f;
  unsigned r = v.u + 0x7FFFu + ((v.u >> 16) & 1u);   // RNE
  return (u16)(r >> 16);
}

__device__ __forceinline__ void gld_lds16(const u16* g, u16* l) {
  __builtin_amdgcn_global_load_lds((const __attribute__((address_space(1))) unsigned int*)g,
                                   (__attribute__((address_space(3))) unsigned int*)l,
                                   16, 0, 0);
}

// per-block expert count + exclusive offset from cnt[8]
__device__ __forceinline__ void cnt_offs(const int* __restrict__ cnt, int e, int& cn, int& gofs) {
  int s = 0, c = 0;
#pragma unroll
  for (int i = 0; i < EE; i++) {
    int v = cnt[i];
    if (i < e) s += v;
    if (i == e) c = v;
  }
  cn = c; gofs = s;
}

// ---------------- fused prep: w13 cvt | w2 cvt | x cvt | router ----------------
__global__ __launch_bounds__(256) void prep(const float* __restrict__ x, const float* __restrict__ gw,
                                            const float* __restrict__ w1, const float* __restrict__ w2,
                                            const float* __restrict__ w3,
                                            ushort4* __restrict__ w13i, ushort4* __restrict__ w2b,
                                            ushort4* __restrict__ xb,
                                            int* __restrict__ cnt, int* __restrict__ tok_list,
                                            float* __restrict__ wt_list) {
  int bid = blockIdx.x;
  if (bid < NB13) {
    // w13i[e][n][h]: f=(n>>5)*16+(n&15), sel=(n>>4)&1 ; sel=0 -> w1, sel=1 -> w3
    int i = bid * 256 + threadIdx.x;
    const int perE = N13 * (HH / 4);
    int e = i / perE;
    int rem = i - e * perE;
    int n = rem / (HH / 4);
    int h4 = rem - n * (HH / 4);
    int f = ((n >> 5) << 4) + (n & 15);
    int sel = (n >> 4) & 1;
    const float* base = sel ? w3 : w1;
    const float4* src = ((const float4*)(base + (size_t)(e * FF + f) * HH)) + h4;
    float4 v = *src;
    ushort4 o; o.x = f2b(v.x); o.y = f2b(v.y); o.z = f2b(v.z); o.w = f2b(v.w);
    w13i[i] = o;
    return;
  }
  bid -= NB13;
  if (bid < NBW2) {
    int i = bid * 256 + threadIdx.x;
    float4 v = ((const float4*)w2)[i];
    ushort4 o; o.x = f2b(v.x); o.y = f2b(v.y); o.z = f2b(v.z); o.w = f2b(v.w);
    w2b[i] = o;
    return;
  }
  bid -= NBW2;
  if (bid < NBX) {
    int i = bid * 256 + threadIdx.x;
    float4 v = ((const float4*)x)[i];
    ushort4 o; o.x = f2b(v.x); o.y = f2b(v.y); o.z = f2b(v.z); o.w = f2b(v.w);
    xb[i] = o;
    return;
  }
  bid -= NBX;
  {
    // router: 4 tokens per block, one wave each
    int lane = threadIdx.x & 63;
    int wv = threadIdx.x >> 6;
    int t = bid * 4 + wv;
    const float* xp = x + (size_t)t * HH;
    float acc[EE];
#pragma unroll
    for (int e = 0; e < EE; e++) acc[e] = 0.f;
    for (int h = lane; h < HH; h += 64) {
      float xv = xp[h];
#pragma unroll
      for (int e = 0; e < EE; e++) acc[e] += xv * gw[e * HH + h];
    }
#pragma unroll
    for (int e = 0; e < EE; e++) {
#pragma unroll
      for (int off = 32; off > 0; off >>= 1) acc[e] += __shfl_xor(acc[e], off, 64);
    }
    if (lane == 0) {
      int i1 = 0;
#pragma unroll
      for (int e = 1; e < EE; e++) if (acc[e] > acc[i1]) i1 = e;
      int i2 = -1;
#pragma unroll
      for (int e = 0; e < EE; e++) {
        if (e == i1) continue;
        if (i2 < 0 || acc[e] > acc[i2]) i2 = e;
      }
      float wA = 1.f / (1.f + __expf(acc[i2] - acc[i1]));
      float wB = 1.f - wA;
      int p1 = atomicAdd(cnt + i1, 1);
      tok_list[i1 * TT + p1] = t; wt_list[i1 * TT + p1] = wA;
      int p2 = atomicAdd(cnt + i2, 1);
      tok_list[i2 * TT + p2] = t; wt_list[i2 * TT + p2] = wB;
    }
  }
}

__global__ __launch_bounds__(256) void pairmap(const int* __restrict__ cnt,
                                               const int* __restrict__ tok_list,
                                               int* __restrict__ tokp) {
  int i = blockIdx.x * 256 + threadIdx.x;   // e*TT + s
  int e = i >> 12;
  int s = i & (TT - 1);
  int cn, gofs;
  cnt_offs(cnt, e, cn, gofs);
  if (s < cn) tokp[gofs + s] = tok_list[i];
}

// ---------------- GEMM A + fused SwiGLU ----------------
__global__ __launch_bounds__(256) void gemm_a(const u16* __restrict__ xb, const u16* __restrict__ w13i,
                                              const int* __restrict__ cnt,
                                              const int* __restrict__ tok_list, const float* __restrict__ wt_list,
                                              u16* __restrict__ gbuf) {
  const int e = blockIdx.x >> 5;           // x = e*32+rt so B-tile-sharing blocks co-reside
  const int rt = blockIdx.x & 31;
  const int ntile = blockIdx.y;            // 0..55
  int cn, gofs;
  cnt_offs(cnt, e, cn, gofs);
  if (rt * BM >= cn) return;

  __shared__ u16 As[BM * BK];   // XOR-swizzled 8-elt granules
  __shared__ u16 Bs[BN * BK];
  __shared__ int toks[BM];
  __shared__ float wts[BM];

  const int tid = threadIdx.x;
  if (tid < BM) {
    int r = rt * BM + tid;
    if (r >= cn) r = cn - 1;
    toks[tid] = tok_list[e * TT + r];
    wts[tid] = wt_list[e * TT + r];
  }
  __syncthreads();

  const u16* aptr[4];
  const u16* bptr[4];
  u16* alds[4];
  u16* blds[4];
#pragma unroll
  for (int i = 0; i < 4; i++) {
    int row = (tid >> 3) + i * 32;
    int c8 = (tid & 7) ^ (row & 7);
    aptr[i] = xb + (size_t)toks[row] * HH + c8 * 8;
    bptr[i] = w13i + ((size_t)e * N13 + (size_t)ntile * BN + row) * HH + c8 * 8;
    alds[i] = As + row * BK + (tid & 7) * 8;
    blds[i] = Bs + row * BK + (tid & 7) * 8;
  }

  const int lane = tid & 63;
  const int wv = tid >> 6;
  const int wr = (wv >> 1) * 64;
  const int wc = (wv & 1) * 64;
  const int fr = lane & 15;
  const int fk8 = lane >> 4;

  floatx4 acc[4][4];
#pragma unroll
  for (int mi = 0; mi < 4; mi++)
#pragma unroll
    for (int ni = 0; ni < 4; ni++)
#pragma unroll
      for (int q = 0; q < 4; q++) acc[mi][ni][q] = 0.f;

  for (int k0 = 0; k0 < HH; k0 += BK) {
#pragma unroll
    for (int i = 0; i < 4; i++) {
      gld_lds16(aptr[i], alds[i]); aptr[i] += BK;
      gld_lds16(bptr[i], blds[i]); bptr[i] += BK;
    }
    __syncthreads();
#pragma unroll
    for (int ks = 0; ks < 2; ks++) {
      int c8 = (ks * 4 + fk8) ^ (fr & 7);
      short8 af[4], bfr[4];
#pragma unroll
      for (int mi = 0; mi < 4; mi++) af[mi] = *(const short8*)&As[(wr + mi * 16 + fr) * BK + c8 * 8];
#pragma unroll
      for (int ni = 0; ni < 4; ni++) bfr[ni] = *(const short8*)&Bs[(wc + ni * 16 + fr) * BK + c8 * 8];
#pragma unroll
      for (int mi = 0; mi < 4; mi++)
#pragma unroll
        for (int ni = 0; ni < 4; ni++)
          acc[mi][ni] = __builtin_amdgcn_mfma_f32_16x16x32_bf16(af[mi], bfr[ni], acc[mi][ni], 0, 0, 0);
    }
    __syncthreads();
  }

  const int cl = lane & 15;
#pragma unroll
  for (int mi = 0; mi < 4; mi++) {
#pragma unroll
    for (int q = 0; q < 4; q++) {
      int r = wr + mi * 16 + (lane >> 4) * 4 + q;
      int gr = rt * BM + r;
      if (gr < cn) {
        float w = wts[r];
        u16* dst = gbuf + (size_t)(gofs + gr) * FF + (size_t)ntile * 64 + wc / 2 + cl;
#pragma unroll
        for (int pg = 0; pg < 2; pg++) {
          float h1 = acc[mi][2 * pg][q];
          float h3 = acc[mi][2 * pg + 1][q];
          float s = h1 * __builtin_amdgcn_rcpf(1.f + __expf(-h1));
          dst[pg * 16] = f2b(s * h3 * w);
        }
      }
    }
  }
}

// ---------------- GEMM B (split-K): out[tok] += g[pair] . w2[e][h][:] ----------------
__global__ __launch_bounds__(256) void gemm_b(const u16* __restrict__ g, const u16* __restrict__ w2b,
                                              const int* __restrict__ cnt,
                                              const int* __restrict__ tokp, float* __restrict__ out) {
  const int e = blockIdx.x >> 5;
  const int rt = blockIdx.x & 31;
  const int ntile = blockIdx.y;            // 0..7
  const int ksp = blockIdx.z;              // 0..3
  int cn, gofs;
  cnt_offs(cnt, e, cn, gofs);
  if (rt * BM >= cn) return;

  __shared__ u16 As[BM * BK];
  __shared__ u16 Bs[BN * BK];
  __shared__ int toks[BM];

  const int tid = threadIdx.x;
  if (tid < BM) {
    int r = rt * BM + tid;
    if (r >= cn) r = cn - 1;
    toks[tid] = tokp[gofs + r];
  }
  __syncthreads();

  const u16* aptr[4];
  const u16* bptr[4];
  u16* alds[4];
  u16* blds[4];
#pragma unroll
  for (int i = 0; i < 4; i++) {
    int row = (tid >> 3) + i * 32;
    int gr = rt * BM + row;
    if (gr >= cn) gr = cn - 1;
    int c8 = (tid & 7) ^ (row & 7);
    aptr[i] = g + (size_t)(gofs + gr) * FF + ksp * KCH + c8 * 8;
    bptr[i] = w2b + ((size_t)e * HH + (size_t)ntile * BN + row) * FF + ksp * KCH + c8 * 8;
    alds[i] = As + row * BK + (tid & 7) * 8;
    blds[i] = Bs + row * BK + (tid & 7) * 8;
  }

  const int lane = tid & 63;
  const int wv = tid >> 6;
  const int wr = (wv >> 1) * 64;
  const int wc = (wv & 1) * 64;
  const int fr = lane & 15;
  const int fk8 = lane >> 4;

  floatx4 acc[4][4];
#pragma unroll
  for (int mi = 0; mi < 4; mi++)
#pragma unroll
    for (int ni = 0; ni < 4; ni++)
#pragma unroll
      for (int q = 0; q < 4; q++) acc[mi][ni][q] = 0.f;

  for (int k0 = 0; k0 < KCH; k0 += BK) {
#pragma unroll
    for (int i = 0; i < 4; i++) {
      gld_lds16(aptr[i], alds[i]); aptr[i] += BK;
      gld_lds16(bptr[i], blds[i]); bptr[i] += BK;
    }
    __syncthreads();
#pragma unroll
    for (int ks = 0; ks < 2; ks++) {
      int c8 = (ks * 4 + fk8) ^ (fr & 7);
      short8 af[4], bfr[4];
#pragma unroll
      for (int mi = 0; mi < 4; mi++) af[mi] = *(const short8*)&As[(wr + mi * 16 + fr) * BK + c8 * 8];
#pragma unroll
      for (int ni = 0; ni < 4; ni++) bfr[ni] = *(const short8*)&Bs[(wc + ni * 16 + fr) * BK + c8 * 8];
#pragma unroll
      for (int mi = 0; mi < 4; mi++)
#pragma unroll
        for (int ni = 0; ni < 4; ni++)
          acc[mi][ni] = __builtin_amdgcn_mfma_f32_16x16x32_bf16(af[mi], bfr[ni], acc[mi][ni], 0, 0, 0);
    }
    __syncthreads();
  }

#pragma unroll
  for (int mi = 0; mi < 4; mi++) {
#pragma unroll
    for (int q = 0; q < 4; q++) {
      int r = wr + mi * 16 + (lane >> 4) * 4 + q;
      int gr = rt * BM + r;
      if (gr < cn) {
        int tk = toks[r];
        float* dst = out + (size_t)tk * HH + (size_t)ntile * BN + wc + (lane & 15);
#pragma unroll
        for (int ni = 0; ni < 4; ni++) atomicAdd(dst + ni * 16, acc[mi][ni][q]);
      }
    }
  }
}

extern "C" void kernel_launch(void* const* d_in, const int* in_sizes, int n_in,
                              void* d_out, int out_size, void* d_ws, size_t ws_size,
                              hipStream_t stream) {
  const float* x  = (const float*)d_in[0];
  const float* gw = (const float*)d_in[1];
  const float* w1 = (const float*)d_in[2];
  const float* w2 = (const float*)d_in[3];
  const float* w3 = (const float*)d_in[4];
  float* out = (float*)d_out;

  char* ws = (char*)d_ws;
  u16* xb    = (u16*)ws;  ws += (size_t)TT * HH * 2;          // 8 MB
  u16* w13i  = (u16*)ws;  ws += (size_t)EE * N13 * HH * 2;    // 117 MB
  u16* w2b   = (u16*)ws;  ws += (size_t)EE * HH * FF * 2;     // 59 MB
  u16* gbuf  = (u16*)ws;  ws += (size_t)TKP * FF * 2;         // 59 MB
  int* cnt   = (int*)ws;  ws += 256;
  int* tok_list = (int*)ws;   ws += (size_t)EE * TT * 4;
  float* wt_list = (float*)ws; ws += (size_t)EE * TT * 4;
  int* tokp  = (int*)ws;  ws += (size_t)TKP * 4;

  hipMemsetAsync(cnt, 0, 256, stream);
  hipMemsetAsync(out, 0, (size_t)TT * HH * 4, stream);

  prep<<<NB13 + NBW2 + NBX + NBR, 256, 0, stream>>>(x, gw, w1, w2, w3,
                                                    (ushort4*)w13i, (ushort4*)w2b, (ushort4*)xb,
                                                    cnt, tok_list, wt_list);
  pairmap<<<(EE * TT) / 256, 256, 0, stream>>>(cnt, tok_list, tokp);

  gemm_a<<<dim3(EE * 32, N13 / BN), 256, 0, stream>>>(xb, w13i, cnt, tok_list, wt_list, gbuf);
  gemm_b<<<dim3(EE * 32, HH / BN, KSPLIT), 256, 0, stream>>>(gbuf, w2b, cnt, tokp, out);
}

// Round 4
// 748.462 us; speedup vs baseline: 1.8166x; 1.8166x over previous
//
#include <hip/hip_runtime.h>
#include <hip/hip_bf16.h>

#define TT   4096
#define HH   1024
#define FF   3584
#define EE   8
#define N13  7168   // 2*FF (interleaved w1/w3 at 16-col granularity)
#define TKP  8192   // TT * top_k

#define BM 128
#define BN 128
#define BK 64
#define KSPLIT 4
#define KCH (FF / KSPLIT)   // 896 = 14 iters of BK

// prep kernel region sizes (blocks of 256)
#define NB13 57344
#define NBW2 28672
#define NBX  4096
#define NBR  1024

typedef unsigned short u16;
typedef __attribute__((ext_vector_type(8))) short short8;
typedef __attribute__((ext_vector_type(4))) float floatx4;

__device__ __forceinline__ u16 f2b(float f) {
  union { float f; unsigned u; } v; v.f = f;
  unsigned r = v.u + 0x7FFFu + ((v.u >> 16) & 1u);   // RNE
  return (u16)(r >> 16);
}

__device__ __forceinline__ void gld_lds16(const u16* g, u16* l) {
  __builtin_amdgcn_global_load_lds((const __attribute__((address_space(1))) unsigned int*)g,
                                   (__attribute__((address_space(3))) unsigned int*)l,
                                   16, 0, 0);
}

// per-block expert count + exclusive offset from cnt[8]
__device__ __forceinline__ void cnt_offs(const int* __restrict__ cnt, int e, int& cn, int& gofs) {
  int s = 0, c = 0;
#pragma unroll
  for (int i = 0; i < EE; i++) {
    int v = cnt[i];
    if (i < e) s += v;
    if (i == e) c = v;
  }
  cn = c; gofs = s;
}

// ---------------- fused prep: w13 cvt | w2 cvt | x cvt | router ----------------
__global__ __launch_bounds__(256) void prep(const float* __restrict__ x, const float* __restrict__ gw,
                                            const float* __restrict__ w1, const float* __restrict__ w2,
                                            const float* __restrict__ w3,
                                            ushort4* __restrict__ w13i, ushort4* __restrict__ w2b,
                                            ushort4* __restrict__ xb,
                                            int* __restrict__ cnt, int* __restrict__ tok_list,
                                            float* __restrict__ wt_list) {
  int bid = blockIdx.x;
  if (bid < NB13) {
    // w13i[e][n][h]: f=(n>>5)*16+(n&15), sel=(n>>4)&1 ; sel=0 -> w1, sel=1 -> w3
    int i = bid * 256 + threadIdx.x;
    const int perE = N13 * (HH / 4);
    int e = i / perE;
    int rem = i - e * perE;
    int n = rem / (HH / 4);
    int h4 = rem - n * (HH / 4);
    int f = ((n >> 5) << 4) + (n & 15);
    int sel = (n >> 4) & 1;
    const float* base = sel ? w3 : w1;
    const float4* src = ((const float4*)(base + (size_t)(e * FF + f) * HH)) + h4;
    float4 v = *src;
    ushort4 o; o.x = f2b(v.x); o.y = f2b(v.y); o.z = f2b(v.z); o.w = f2b(v.w);
    w13i[i] = o;
    return;
  }
  bid -= NB13;
  if (bid < NBW2) {
    int i = bid * 256 + threadIdx.x;
    float4 v = ((const float4*)w2)[i];
    ushort4 o; o.x = f2b(v.x); o.y = f2b(v.y); o.z = f2b(v.z); o.w = f2b(v.w);
    w2b[i] = o;
    return;
  }
  bid -= NBW2;
  if (bid < NBX) {
    int i = bid * 256 + threadIdx.x;
    float4 v = ((const float4*)x)[i];
    ushort4 o; o.x = f2b(v.x); o.y = f2b(v.y); o.z = f2b(v.z); o.w = f2b(v.w);
    xb[i] = o;
    return;
  }
  bid -= NBX;
  {
    // router: 4 tokens per block, one wave each
    int lane = threadIdx.x & 63;
    int wv = threadIdx.x >> 6;
    int t = bid * 4 + wv;
    const float* xp = x + (size_t)t * HH;
    float acc[EE];
#pragma unroll
    for (int e = 0; e < EE; e++) acc[e] = 0.f;
    for (int h = lane; h < HH; h += 64) {
      float xv = xp[h];
#pragma unroll
      for (int e = 0; e < EE; e++) acc[e] += xv * gw[e * HH + h];
    }
#pragma unroll
    for (int e = 0; e < EE; e++) {
#pragma unroll
      for (int off = 32; off > 0; off >>= 1) acc[e] += __shfl_xor(acc[e], off, 64);
    }
    if (lane == 0) {
      int i1 = 0;
#pragma unroll
      for (int e = 1; e < EE; e++) if (acc[e] > acc[i1]) i1 = e;
      int i2 = -1;
#pragma unroll
      for (int e = 0; e < EE; e++) {
        if (e == i1) continue;
        if (i2 < 0 || acc[e] > acc[i2]) i2 = e;
      }
      float wA = 1.f / (1.f + __expf(acc[i2] - acc[i1]));
      float wB = 1.f - wA;
      int p1 = atomicAdd(cnt + i1, 1);
      tok_list[i1 * TT + p1] = t; wt_list[i1 * TT + p1] = wA;
      int p2 = atomicAdd(cnt + i2, 1);
      tok_list[i2 * TT + p2] = t; wt_list[i2 * TT + p2] = wB;
    }
  }
}

__global__ __launch_bounds__(256) void pairmap(const int* __restrict__ cnt,
                                               const int* __restrict__ tok_list,
                                               int* __restrict__ tokp) {
  int i = blockIdx.x * 256 + threadIdx.x;   // e*TT + s
  int e = i >> 12;
  int s = i & (TT - 1);
  int cn, gofs;
  cnt_offs(cnt, e, cn, gofs);
  if (s < cn) tokp[gofs + s] = tok_list[i];
}

// ---------------- GEMM A + fused SwiGLU ----------------
// grid: x = ntile (fastest -> consecutive blocks share A tile, stream B once)
__global__ __launch_bounds__(256) void gemm_a(const u16* __restrict__ xb, const u16* __restrict__ w13i,
                                              const int* __restrict__ cnt,
                                              const int* __restrict__ tok_list, const float* __restrict__ wt_list,
                                              u16* __restrict__ gbuf) {
  const int ntile = blockIdx.x;            // 0..55
  const int e = blockIdx.y >> 5;
  const int rt = blockIdx.y & 31;
  int cn, gofs;
  cnt_offs(cnt, e, cn, gofs);
  if (rt * BM >= cn) return;

  __shared__ u16 As[BM * BK];   // XOR-swizzled 8-elt granules
  __shared__ u16 Bs[BN * BK];
  __shared__ int toks[BM];
  __shared__ float wts[BM];

  const int tid = threadIdx.x;
  if (tid < BM) {
    int r = rt * BM + tid;
    if (r >= cn) r = cn - 1;
    toks[tid] = tok_list[e * TT + r];
    wts[tid] = wt_list[e * TT + r];
  }
  __syncthreads();

  const u16* aptr[4];
  const u16* bptr[4];
  u16* alds[4];
  u16* blds[4];
#pragma unroll
  for (int i = 0; i < 4; i++) {
    int row = (tid >> 3) + i * 32;
    int c8 = (tid & 7) ^ (row & 7);
    aptr[i] = xb + (size_t)toks[row] * HH + c8 * 8;
    bptr[i] = w13i + ((size_t)e * N13 + (size_t)ntile * BN + row) * HH + c8 * 8;
    alds[i] = As + row * BK + (tid & 7) * 8;
    blds[i] = Bs + row * BK + (tid & 7) * 8;
  }

  const int lane = tid & 63;
  const int wv = tid >> 6;
  const int wr = (wv >> 1) * 64;
  const int wc = (wv & 1) * 64;
  const int fr = lane & 15;
  const int fk8 = lane >> 4;

  floatx4 acc[4][4];
#pragma unroll
  for (int mi = 0; mi < 4; mi++)
#pragma unroll
    for (int ni = 0; ni < 4; ni++)
#pragma unroll
      for (int q = 0; q < 4; q++) acc[mi][ni][q] = 0.f;

  for (int k0 = 0; k0 < HH; k0 += BK) {
#pragma unroll
    for (int i = 0; i < 4; i++) {
      gld_lds16(aptr[i], alds[i]); aptr[i] += BK;
      gld_lds16(bptr[i], blds[i]); bptr[i] += BK;
    }
    __syncthreads();
#pragma unroll
    for (int ks = 0; ks < 2; ks++) {
      int c8 = (ks * 4 + fk8) ^ (fr & 7);
      short8 af[4], bfr[4];
#pragma unroll
      for (int mi = 0; mi < 4; mi++) af[mi] = *(const short8*)&As[(wr + mi * 16 + fr) * BK + c8 * 8];
#pragma unroll
      for (int ni = 0; ni < 4; ni++) bfr[ni] = *(const short8*)&Bs[(wc + ni * 16 + fr) * BK + c8 * 8];
#pragma unroll
      for (int mi = 0; mi < 4; mi++)
#pragma unroll
        for (int ni = 0; ni < 4; ni++)
          acc[mi][ni] = __builtin_amdgcn_mfma_f32_16x16x32_bf16(af[mi], bfr[ni], acc[mi][ni], 0, 0, 0);
    }
    __syncthreads();
  }

  const int cl = lane & 15;
#pragma unroll
  for (int mi = 0; mi < 4; mi++) {
#pragma unroll
    for (int q = 0; q < 4; q++) {
      int r = wr + mi * 16 + (lane >> 4) * 4 + q;
      int gr = rt * BM + r;
      if (gr < cn) {
        float w = wts[r];
        u16* dst = gbuf + (size_t)(gofs + gr) * FF + (size_t)ntile * 64 + wc / 2 + cl;
#pragma unroll
        for (int pg = 0; pg < 2; pg++) {
          float h1 = acc[mi][2 * pg][q];
          float h3 = acc[mi][2 * pg + 1][q];
          float s = h1 * __builtin_amdgcn_rcpf(1.f + __expf(-h1));
          dst[pg * 16] = f2b(s * h3 * w);
        }
      }
    }
  }
}

// ---------------- GEMM B (split-K): out[tok] += g[pair] . w2[e][h][:] ----------------
// grid: x = ntile fastest, z = ksp slowest (each z-slice keeps round-2 locality)
__global__ __launch_bounds__(256) void gemm_b(const u16* __restrict__ g, const u16* __restrict__ w2b,
                                              const int* __restrict__ cnt,
                                              const int* __restrict__ tokp, float* __restrict__ out) {
  const int ntile = blockIdx.x;            // 0..7
  const int e = blockIdx.y >> 5;
  const int rt = blockIdx.y & 31;
  const int ksp = blockIdx.z;              // 0..3
  int cn, gofs;
  cnt_offs(cnt, e, cn, gofs);
  if (rt * BM >= cn) return;

  __shared__ u16 As[BM * BK];
  __shared__ u16 Bs[BN * BK];
  __shared__ int toks[BM];

  const int tid = threadIdx.x;
  if (tid < BM) {
    int r = rt * BM + tid;
    if (r >= cn) r = cn - 1;
    toks[tid] = tokp[gofs + r];
  }
  __syncthreads();

  const u16* aptr[4];
  const u16* bptr[4];
  u16* alds[4];
  u16* blds[4];
#pragma unroll
  for (int i = 0; i < 4; i++) {
    int row = (tid >> 3) + i * 32;
    int gr = rt * BM + row;
    if (gr >= cn) gr = cn - 1;
    int c8 = (tid & 7) ^ (row & 7);
    aptr[i] = g + (size_t)(gofs + gr) * FF + ksp * KCH + c8 * 8;
    bptr[i] = w2b + ((size_t)e * HH + (size_t)ntile * BN + row) * FF + ksp * KCH + c8 * 8;
    alds[i] = As + row * BK + (tid & 7) * 8;
    blds[i] = Bs + row * BK + (tid & 7) * 8;
  }

  const int lane = tid & 63;
  const int wv = tid >> 6;
  const int wr = (wv >> 1) * 64;
  const int wc = (wv & 1) * 64;
  const int fr = lane & 15;
  const int fk8 = lane >> 4;

  floatx4 acc[4][4];
#pragma unroll
  for (int mi = 0; mi < 4; mi++)
#pragma unroll
    for (int ni = 0; ni < 4; ni++)
#pragma unroll
      for (int q = 0; q < 4; q++) acc[mi][ni][q] = 0.f;

  for (int k0 = 0; k0 < KCH; k0 += BK) {
#pragma unroll
    for (int i = 0; i < 4; i++) {
      gld_lds16(aptr[i], alds[i]); aptr[i] += BK;
      gld_lds16(bptr[i], blds[i]); bptr[i] += BK;
    }
    __syncthreads();
#pragma unroll
    for (int ks = 0; ks < 2; ks++) {
      int c8 = (ks * 4 + fk8) ^ (fr & 7);
      short8 af[4], bfr[4];
#pragma unroll
      for (int mi = 0; mi < 4; mi++) af[mi] = *(const short8*)&As[(wr + mi * 16 + fr) * BK + c8 * 8];
#pragma unroll
      for (int ni = 0; ni < 4; ni++) bfr[ni] = *(const short8*)&Bs[(wc + ni * 16 + fr) * BK + c8 * 8];
#pragma unroll
      for (int mi = 0; mi < 4; mi++)
#pragma unroll
        for (int ni = 0; ni < 4; ni++)
          acc[mi][ni] = __builtin_amdgcn_mfma_f32_16x16x32_bf16(af[mi], bfr[ni], acc[mi][ni], 0, 0, 0);
    }
    __syncthreads();
  }

#pragma unroll
  for (int mi = 0; mi < 4; mi++) {
#pragma unroll
    for (int q = 0; q < 4; q++) {
      int r = wr + mi * 16 + (lane >> 4) * 4 + q;
      int gr = rt * BM + r;
      if (gr < cn) {
        int tk = toks[r];
        float* dst = out + (size_t)tk * HH + (size_t)ntile * BN + wc + (lane & 15);
#pragma unroll
        for (int ni = 0; ni < 4; ni++) atomicAdd(dst + ni * 16, acc[mi][ni][q]);
      }
    }
  }
}

extern "C" void kernel_launch(void* const* d_in, const int* in_sizes, int n_in,
                              void* d_out, int out_size, void* d_ws, size_t ws_size,
                              hipStream_t stream) {
  const float* x  = (const float*)d_in[0];
  const float* gw = (const float*)d_in[1];
  const float* w1 = (const float*)d_in[2];
  const float* w2 = (const float*)d_in[3];
  const float* w3 = (const float*)d_in[4];
  float* out = (float*)d_out;

  char* ws = (char*)d_ws;
  u16* xb    = (u16*)ws;  ws += (size_t)TT * HH * 2;          // 8 MB
  u16* w13i  = (u16*)ws;  ws += (size_t)EE * N13 * HH * 2;    // 117 MB
  u16* w2b   = (u16*)ws;  ws += (size_t)EE * HH * FF * 2;     // 59 MB
  u16* gbuf  = (u16*)ws;  ws += (size_t)TKP * FF * 2;         // 59 MB
  int* cnt   = (int*)ws;  ws += 256;
  int* tok_list = (int*)ws;   ws += (size_t)EE * TT * 4;
  float* wt_list = (float*)ws; ws += (size_t)EE * TT * 4;
  int* tokp  = (int*)ws;  ws += (size_t)TKP * 4;

  hipMemsetAsync(cnt, 0, 256, stream);
  hipMemsetAsync(out, 0, (size_t)TT * HH * 4, stream);

  prep<<<NB13 + NBW2 + NBX + NBR, 256, 0, stream>>>(x, gw, w1, w2, w3,
                                                    (ushort4*)w13i, (ushort4*)w2b, (ushort4*)xb,
                                                    cnt, tok_list, wt_list);
  pairmap<<<(EE * TT) / 256, 256, 0, stream>>>(cnt, tok_list, tokp);

  gemm_a<<<dim3(N13 / BN, EE * (TT / BM)), 256, 0, stream>>>(xb, w13i, cnt, tok_list, wt_list, gbuf);
  gemm_b<<<dim3(HH / BN, EE * (TT / BM), KSPLIT), 256, 0, stream>>>(gbuf, w2b, cnt, tokp, out);
}